// Round 3
// baseline (284.701 us; speedup 1.0000x reference)
//
#include <hip/hip_runtime.h>

// Problem constants (from reference): B=8, C=3, H=512, W=512
constexpr int Cc = 3;
constexpr int Hc = 512;
constexpr int Wc = 512;
constexpr int HW = Hc * Wc;            // 262144 = 2^18
constexpr int NPIX = 8 * HW;           // 2097152

constexpr int TILE   = 512;            // pixels per block (2 per thread)
constexpr int NBLK   = NPIX / TILE;    // 4096 blocks
constexpr int TF4    = TILE * 9 / 4;   // 1152 float4 of sigma per tile (18 KB)

__global__ __launch_bounds__(256) void map_loss_main(
    const float* __restrict__ target,
    const float* __restrict__ mu,
    const float* __restrict__ sigma_y,
    double* __restrict__ ws_sum,
    unsigned int* __restrict__ ws_max)
{
    __shared__ float4 smem[TF4];       // 18432 B

    const int t = threadIdx.x;
    const long long tile = (long long)blockIdx.x * TILE;   // first pixel of tile

    // ---- stage sigma tile: pure block-coalesced float4 stream ----
    // tile*9 floats = tile*9/4 float4 (integral since TILE*9 % 4 == 0)
    const float4* s4 = (const float4*)sigma_y + (long long)blockIdx.x * TF4;
    #pragma unroll
    for (int j = 0; j < 4; ++j)
        smem[j * 256 + t] = s4[j * 256 + t];
    if (t < TF4 - 1024)                 // 128 threads = waves 0,1 -> wave-uniform
        smem[1024 + t] = s4[1024 + t];
    __syncthreads();

    // ---- per-thread: 2 consecutive pixels ----
    const int p0 = (int)tile + 2 * t;
    const int b  = p0 >> 18;            // / HW
    const int hw = p0 & (HW - 1);       // % HW (even)
    const long long base = (long long)b * (Cc * HW) + hw;

    // target/mu: 3 channels as coalesced float2 (8 B lane stride)
    const float2* tg = (const float2*)(target + base);
    const float2* mm = (const float2*)(mu + base);
    float2 d0 = tg[0];        float2 m0 = mm[0];
    float2 d1 = tg[HW / 2];   float2 m1 = mm[HW / 2];
    float2 d2 = tg[HW];       float2 m2 = mm[HW];
    const float T0[2] = {d0.x - m0.x, d0.y - m0.y};
    const float T1[2] = {d1.x - m1.x, d1.y - m1.y};
    const float T2[2] = {d2.x - m2.x, d2.y - m2.y};

    // sigma for my 2 pixels: 18 consecutive floats from LDS
    // (lane stride 18 floats -> banks 18*l mod 32 distinct over 16 lanes,
    //  2-way aliasing across half-phase = free)
    const float* sp = (const float*)smem + (size_t)t * 18;
    float S[18];
    #pragma unroll
    for (int k = 0; k < 18; ++k) S[k] = sp[k];

    double local_sum = 0.0;
    float  local_max = 0.0f;

    #pragma unroll
    for (int i = 0; i < 2; ++i) {
        const float* s = S + i * 9;
        float s00 = s[0], s01 = s[1], s02 = s[2];
        float s11 = s[4], s12 = s[5], s22 = s[8];

        // adjugate (symmetric)
        float a00 = s11 * s22 - s12 * s12;
        float a01 = s02 * s12 - s01 * s22;
        float a02 = s01 * s12 - s02 * s11;
        float a11 = s00 * s22 - s02 * s02;
        float a12 = s01 * s02 - s00 * s12;
        float a22 = s00 * s11 - s01 * s01;

        float det = s00 * a00 + s01 * a01 + s02 * a02;

        float t0 = T0[i], t1 = T1[i], t2 = T2[i];
        float quad = t0 * t0 * a00 + t1 * t1 * a11 + t2 * t2 * a22
                   + 2.0f * (t0 * t1 * a01 + t0 * t2 * a02 + t1 * t2 * a12);

        float t1term = 0.5f * quad / det;
        float t2term = 0.5f * logf(det);

        local_sum += (double)(t1term + t2term);
        local_max = fmaxf(local_max, t1term);
    }

    // ---- wave (64-lane) reduction ----
    for (int off = 32; off > 0; off >>= 1) {
        local_sum += __shfl_down(local_sum, off, 64);
        local_max = fmaxf(local_max, __shfl_down(local_max, off, 64));
    }

    __shared__ double ssum[4];
    __shared__ float  smax[4];
    int wave = t >> 6;
    int lane = t & 63;
    if (lane == 0) { ssum[wave] = local_sum; smax[wave] = local_max; }
    __syncthreads();

    if (t == 0) {
        double bs = ssum[0] + ssum[1] + ssum[2] + ssum[3];
        float  bm = fmaxf(fmaxf(smax[0], smax[1]), fmaxf(smax[2], smax[3]));
        atomicAdd(ws_sum, bs);
        // t1 >= 0 (SPD) so unsigned bit-pattern ordering == float ordering
        atomicMax(ws_max, __float_as_uint(bm));
    }
}

__global__ void map_loss_finalize(const double* __restrict__ ws_sum,
                                  const unsigned int* __restrict__ ws_max,
                                  float* __restrict__ out)
{
    float m = __uint_as_float(*ws_max);
    double mean = *ws_sum / (double)NPIX;
    out[0] = (m > 1e8f) ? 0.0f : (float)mean;
}

extern "C" void kernel_launch(void* const* d_in, const int* in_sizes, int n_in,
                              void* d_out, int out_size, void* d_ws, size_t ws_size,
                              hipStream_t stream) {
    const float* target  = (const float*)d_in[0];
    const float* mu      = (const float*)d_in[1];
    // d_in[2] = sigma_mu (unused), d_in[3] = sigma_n (unused)
    const float* sigma_y = (const float*)d_in[4];
    float* out = (float*)d_out;

    double*       ws_sum = (double*)d_ws;
    unsigned int* ws_max = (unsigned int*)((char*)d_ws + 8);

    // ws is re-poisoned to 0xAA before every launch — zero what we use.
    hipMemsetAsync(d_ws, 0, 16, stream);

    map_loss_main<<<NBLK, 256, 0, stream>>>(target, mu, sigma_y, ws_sum, ws_max);
    map_loss_finalize<<<1, 1, 0, stream>>>(ws_sum, ws_max, out);
}

// Round 4
// 216.299 us; speedup vs baseline: 1.3162x; 1.3162x over previous
//
#include <hip/hip_runtime.h>

// Problem constants (from reference): B=8, C=3, H=512, W=512
constexpr int Cc = 3;
constexpr int Hc = 512;
constexpr int Wc = 512;
constexpr int HW = Hc * Wc;            // 262144 = 2^18
constexpr int NPIX = 8 * HW;           // 2097152
constexpr int NGRP = NPIX / 4;         // 524288 groups of 4 consecutive pixels
constexpr int NBLK = NGRP / 256;       // 2048 blocks

// ws layout: [0, 2048) doubles = per-block partial sums (16 KB)
//            then 2048 floats = per-block partial maxes (8 KB)

__global__ __launch_bounds__(256) void map_loss_main(
    const float* __restrict__ target,
    const float* __restrict__ mu,
    const float* __restrict__ sigma_y,
    double* __restrict__ part_sum,
    float* __restrict__ part_max)
{
    double local_sum = 0.0;
    float local_max = 0.0f;

    int g = blockIdx.x * blockDim.x + threadIdx.x;   // one group of 4 pixels
    {
        int p0 = g << 2;                 // first pixel of group (multiple of 4)
        int b  = p0 >> 18;               // / HW
        int hw = p0 & (HW - 1);          // % HW  (multiple of 4)
        long long base = (long long)b * (Cc * HW) + hw;

        // target/mu: 3 channels, float4 per channel — fully coalesced
        const float4* tg = (const float4*)(target + base);
        const float4* mm = (const float4*)(mu + base);
        float4 d0 = tg[0];            float4 m0 = mm[0];
        float4 d1 = tg[HW / 4];       float4 m1 = mm[HW / 4];
        float4 d2 = tg[2 * HW / 4];   float4 m2 = mm[2 * HW / 4];
        d0.x -= m0.x; d0.y -= m0.y; d0.z -= m0.z; d0.w -= m0.w;
        d1.x -= m1.x; d1.y -= m1.y; d1.z -= m1.z; d1.w -= m1.w;
        d2.x -= m2.x; d2.y -= m2.y; d2.z -= m2.z; d2.w -= m2.w;

        // sigma_y: 4 pixels * 9 floats = 144 B = 9 aligned float4 loads
        union { float4 v[9]; float f[36]; } S;
        const float4* s4 = (const float4*)(sigma_y + (long long)p0 * 9);
        #pragma unroll
        for (int i = 0; i < 9; ++i) S.v[i] = s4[i];

        const float T0[4] = {d0.x, d0.y, d0.z, d0.w};
        const float T1[4] = {d1.x, d1.y, d1.z, d1.w};
        const float T2[4] = {d2.x, d2.y, d2.z, d2.w};

        #pragma unroll
        for (int i = 0; i < 4; ++i) {
            const float* s = S.f + i * 9;
            float s00 = s[0], s01 = s[1], s02 = s[2];
            float s11 = s[4], s12 = s[5], s22 = s[8];

            // adjugate (symmetric)
            float a00 = s11 * s22 - s12 * s12;
            float a01 = s02 * s12 - s01 * s22;
            float a02 = s01 * s12 - s02 * s11;
            float a11 = s00 * s22 - s02 * s02;
            float a12 = s01 * s02 - s00 * s12;
            float a22 = s00 * s11 - s01 * s01;

            float det = s00 * a00 + s01 * a01 + s02 * a02;

            float t0 = T0[i], t1 = T1[i], t2 = T2[i];
            float quad = t0 * t0 * a00 + t1 * t1 * a11 + t2 * t2 * a22
                       + 2.0f * (t0 * t1 * a01 + t0 * t2 * a02 + t1 * t2 * a12);

            float t1term = 0.5f * quad / det;
            float t2term = 0.5f * logf(det);

            local_sum += (double)(t1term + t2term);
            local_max = fmaxf(local_max, t1term);
        }
    }

    // wave (64-lane) reduction
    for (int off = 32; off > 0; off >>= 1) {
        local_sum += __shfl_down(local_sum, off, 64);
        local_max = fmaxf(local_max, __shfl_down(local_max, off, 64));
    }

    __shared__ double ssum[4];
    __shared__ float  smax[4];
    int wave = threadIdx.x >> 6;
    int lane = threadIdx.x & 63;
    if (lane == 0) { ssum[wave] = local_sum; smax[wave] = local_max; }
    __syncthreads();

    if (threadIdx.x == 0) {
        // per-block partials to DISTINCT addresses — no atomics, no contention
        part_sum[blockIdx.x] = ssum[0] + ssum[1] + ssum[2] + ssum[3];
        part_max[blockIdx.x] = fmaxf(fmaxf(smax[0], smax[1]), fmaxf(smax[2], smax[3]));
    }
}

__global__ __launch_bounds__(256) void map_loss_finalize(
    const double* __restrict__ part_sum,
    const float* __restrict__ part_max,
    float* __restrict__ out)
{
    double s = 0.0;
    float m = 0.0f;
    for (int i = threadIdx.x; i < NBLK; i += 256) {
        s += part_sum[i];
        m = fmaxf(m, part_max[i]);
    }

    for (int off = 32; off > 0; off >>= 1) {
        s += __shfl_down(s, off, 64);
        m = fmaxf(m, __shfl_down(m, off, 64));
    }

    __shared__ double ssum[4];
    __shared__ float  smax[4];
    int wave = threadIdx.x >> 6;
    int lane = threadIdx.x & 63;
    if (lane == 0) { ssum[wave] = s; smax[wave] = m; }
    __syncthreads();

    if (threadIdx.x == 0) {
        double bs = ssum[0] + ssum[1] + ssum[2] + ssum[3];
        float  bm = fmaxf(fmaxf(smax[0], smax[1]), fmaxf(smax[2], smax[3]));
        out[0] = (bm > 1e8f) ? 0.0f : (float)(bs / (double)NPIX);
    }
}

extern "C" void kernel_launch(void* const* d_in, const int* in_sizes, int n_in,
                              void* d_out, int out_size, void* d_ws, size_t ws_size,
                              hipStream_t stream) {
    const float* target  = (const float*)d_in[0];
    const float* mu      = (const float*)d_in[1];
    // d_in[2] = sigma_mu (unused), d_in[3] = sigma_n (unused)
    const float* sigma_y = (const float*)d_in[4];
    float* out = (float*)d_out;

    double* part_sum = (double*)d_ws;
    float*  part_max = (float*)((char*)d_ws + NBLK * sizeof(double));
    // every slot is written unconditionally by its block — no pre-zeroing needed

    map_loss_main<<<NBLK, 256, 0, stream>>>(target, mu, sigma_y, part_sum, part_max);
    map_loss_finalize<<<1, 256, 0, stream>>>(part_sum, part_max, out);
}